// Round 14
// baseline (249.807 us; speedup 1.0000x reference)
//
#include <hip/hip_runtime.h>

#define THREADS 256
#define NB 256                  // nodes per bucket
#define NB_SHIFT 8
#define TILE_E 1024             // edges per sort tile
#define EPT 2                   // edges per thread in tilesort (TILE_E/512)
#define BMAXPAD 512             // padded bucket-hist size in tilesort
#define WT_LD 136               // padded K stride for packed weights

typedef unsigned short ushort_t;
typedef __attribute__((ext_vector_type(8))) short bf16x8;
typedef __attribute__((ext_vector_type(4))) float f32x4;

__device__ __forceinline__ unsigned short f2bf(float f) {
    unsigned u = __float_as_uint(f);
    u += 0x7fff + ((u >> 16) & 1);   // round-to-nearest-even
    return (unsigned short)(u >> 16);
}
__device__ __forceinline__ float bf2f(unsigned short s) {
    return __uint_as_float((unsigned)s << 16);
}
__device__ __forceinline__ float4 bf4_to_f4(ushort4 u) {
    return make_float4(bf2f(u.x), bf2f(u.y), bf2f(u.z), bf2f(u.w));
}
__device__ __forceinline__ ushort4 f4_to_bf4(float4 v) {
    ushort4 o;
    o.x = f2bf(v.x); o.y = f2bf(v.y); o.z = f2bf(v.z); o.w = f2bf(v.w);
    return o;
}
// pack two f32 -> u32 of two bf16 (lo first)
__device__ __forceinline__ unsigned pack_bf2(float a, float b) {
    return (unsigned)f2bf(a) | ((unsigned)f2bf(b) << 16);
}
// junk-mantissa pair accumulate: lo exact, hi carries <=2^-8 rel mantissa noise
__device__ __forceinline__ void acc_pair(unsigned u, float& lo, float& hi) {
    lo += __uint_as_float(u << 16);
    hi += __uint_as_float(u);
}

// ---------------------------------------------------------------------------
// Edge-index dtype detection.
// ---------------------------------------------------------------------------
__global__ __launch_bounds__(64)
void detect_kernel(const unsigned* __restrict__ ei_words, int* __restrict__ flag) {
    if (threadIdx.x == 0 && blockIdx.x == 0) {
        int allzero = 1;
        for (int i = 0; i < 64; ++i) {
            if (ei_words[2 * i + 1] != 0u) { allzero = 0; break; }
        }
        *flag = allzero;
    }
}

__device__ __forceinline__ void load_edge(const void* ei, int is64, int E, int i,
                                          int& s, int& t) {
    if (is64) {
        const long long* p = (const long long*)ei;
        s = (int)p[i];
        t = (int)p[E + i];
    } else {
        const int* p = (const int*)ei;
        s = p[i];
        t = p[E + i];
    }
}

// ---------------------------------------------------------------------------
// Tile sort: block t owns edges [t*TILE_E, (t+1)*TILE_E). 512 threads, EPT=2.
// ---------------------------------------------------------------------------
__global__ __launch_bounds__(512)
void tilesort_kernel(const void* __restrict__ ei, const int* __restrict__ flag,
                     unsigned* __restrict__ tbuf, int* __restrict__ tcnt,
                     int* __restrict__ tstart, int E, int B) {
    __shared__ int hist[BMAXPAD];
    __shared__ int wsum[8];
    const int t   = blockIdx.x;
    const int e0  = t * TILE_E;
    const int is64 = *flag;
    unsigned w[EPT];
    unsigned short bk[EPT];
    hist[threadIdx.x] = 0;
    __syncthreads();
#pragma unroll
    for (int k = 0; k < EPT; ++k) {
        const int i = e0 + k * 512 + (int)threadIdx.x;
        bk[k] = 0xFFFFu;
        w[k]  = 0u;
        if (i < E) {
            int s, d;
            load_edge(ei, is64, E, i, s, d);
            w[k]  = (unsigned)s | ((unsigned)(d & (NB - 1)) << 17);
            bk[k] = (unsigned short)(d >> NB_SHIFT);
            atomicAdd(&hist[bk[k]], 1);
        }
    }
    __syncthreads();
    const int lane = threadIdx.x & 63;
    const int wid  = threadIdx.x >> 6;     // 0..7
    const int v = hist[threadIdx.x];
    int incl = v;
#pragma unroll
    for (int off = 1; off < 64; off <<= 1) {
        int tt = __shfl_up(incl, off, 64);
        if (lane >= off) incl += tt;
    }
    if (lane == 63) wsum[wid] = incl;
    __syncthreads();   // wsum ready; all hist reads complete
    int woff = 0;
    for (int ww = 0; ww < wid; ++ww) woff += wsum[ww];
    const int excl = woff + incl - v;
    hist[threadIdx.x] = excl;              // becomes write-pointer array
    const int b = threadIdx.x;
    if (b < B) { tcnt[(size_t)t * B + b] = v; tstart[(size_t)t * B + b] = excl; }
    __syncthreads();
#pragma unroll
    for (int k = 0; k < EPT; ++k) {
        if (bk[k] != 0xFFFFu) {
            const int pos = atomicAdd(&hist[bk[k]], 1);
            tbuf[(size_t)t * TILE_E + pos] = w[k];
        }
    }
}

// ---------------------------------------------------------------------------
// Transpose tcnt/tstart [T][B] -> [B][T] via 32x32 LDS tiles.
// ---------------------------------------------------------------------------
__global__ __launch_bounds__(256)
void transpose2_kernel(const int* __restrict__ tcnt, const int* __restrict__ tstart,
                       int* __restrict__ tcntT, int* __restrict__ tstartT,
                       int T, int B) {
    __shared__ int ta[32][33];
    __shared__ int tb[32][33];
    const int bx = blockIdx.x;            // along B
    const int by = blockIdx.y;            // along T
    const int tx = threadIdx.x & 31;
    const int ty = threadIdx.x >> 5;      // 0..7
#pragma unroll
    for (int r = 0; r < 4; ++r) {
        const int trow = by * 32 + ty * 4 + r;
        const int bcol = bx * 32 + tx;
        if (trow < T && bcol < B) {
            ta[ty * 4 + r][tx] = tcnt[(size_t)trow * B + bcol];
            tb[ty * 4 + r][tx] = tstart[(size_t)trow * B + bcol];
        }
    }
    __syncthreads();
#pragma unroll
    for (int r = 0; r < 4; ++r) {
        const int brow = bx * 32 + ty * 4 + r;
        const int tcol = by * 32 + tx;
        if (brow < B && tcol < T) {
            tcntT[(size_t)brow * T + tcol]   = ta[tx][ty * 4 + r];
            tstartT[(size_t)brow * T + tcol] = tb[tx][ty * 4 + r];
        }
    }
}

// ---------------------------------------------------------------------------
// Scan over tcntT (bucket-major) -> hbase.
// ---------------------------------------------------------------------------
__global__ __launch_bounds__(256)
void scan_partial_kernel(const int* __restrict__ cnt, int* __restrict__ bsum, int n) {
    const int base = blockIdx.x * 1024;
    int v = 0;
    for (int i = threadIdx.x; i < 1024; i += 256) {
        const int idx = base + i;
        v += (idx < n) ? cnt[idx] : 0;
    }
#pragma unroll
    for (int off = 32; off > 0; off >>= 1) v += __shfl_down(v, off, 64);
    __shared__ int ws[4];
    if ((threadIdx.x & 63) == 0) ws[threadIdx.x >> 6] = v;
    __syncthreads();
    if (threadIdx.x == 0) bsum[blockIdx.x] = ws[0] + ws[1] + ws[2] + ws[3];
}

__global__ __launch_bounds__(1024)
void scan_bsum_kernel(int* __restrict__ bsum, int* __restrict__ total, int nb) {
    __shared__ int wsum[16];
    const int lane = threadIdx.x & 63;
    const int wid  = threadIdx.x >> 6;    // 0..15
    int run = 0;
    for (int base = 0; base < nb; base += 1024) {
        const int i = base + (int)threadIdx.x;
        const int v = (i < nb) ? bsum[i] : 0;
        int incl = v;
#pragma unroll
        for (int off = 1; off < 64; off <<= 1) {
            int t = __shfl_up(incl, off, 64);
            if (lane >= off) incl += t;
        }
        if (lane == 63) wsum[wid] = incl;
        __syncthreads();
        if (wid == 0) {
            int wv = (lane < 16) ? wsum[lane] : 0;
#pragma unroll
            for (int off = 1; off < 16; off <<= 1) {
                int t = __shfl_up(wv, off, 64);
                if (lane >= off) wv += t;
            }
            if (lane < 16) wsum[lane] = wv;
        }
        __syncthreads();
        const int wbase = (wid > 0) ? wsum[wid - 1] : 0;
        const int tot   = wsum[15];
        if (i < nb) bsum[i] = run + wbase + incl - v;
        run += tot;
        __syncthreads();
    }
    if (threadIdx.x == 0) *total = run;
}

__global__ __launch_bounds__(256)
void scan_final_kernel(const int* __restrict__ cnt, const int* __restrict__ bsum,
                       int* __restrict__ outp, int n) {
    const int base = blockIdx.x * 1024 + threadIdx.x * 4;
    int a0 = 0, a1 = 0, a2 = 0, a3 = 0;
    if (base + 0 < n) a0 = cnt[base + 0];
    if (base + 1 < n) a1 = cnt[base + 1];
    if (base + 2 < n) a2 = cnt[base + 2];
    if (base + 3 < n) a3 = cnt[base + 3];
    const int mysum = a0 + a1 + a2 + a3;
    const int lane = threadIdx.x & 63;
    const int wid  = threadIdx.x >> 6;
    int incl = mysum;
#pragma unroll
    for (int off = 1; off < 64; off <<= 1) {
        int t = __shfl_up(incl, off, 64);
        if (lane >= off) incl += t;
    }
    __shared__ int ws[4];
    if (lane == 63) ws[wid] = incl;
    __syncthreads();
    int woff = 0;
    for (int w = 0; w < wid; ++w) woff += ws[w];
    int pre = bsum[blockIdx.x] + woff + (incl - mysum);
    if (base + 0 < n) outp[base + 0] = pre; pre += a0;
    if (base + 1 < n) outp[base + 1] = pre; pre += a1;
    if (base + 2 < n) outp[base + 2] = pre; pre += a2;
    if (base + 3 < n) outp[base + 3] = pre;
}

// ---------------------------------------------------------------------------
// Fine sort: one 512-thread block per bucket. esrc stores BYTE offsets
// (src*256) of the source's 256B interleaved feature row.
// ---------------------------------------------------------------------------
__global__ __launch_bounds__(512)
void finesort_kernel(const unsigned* __restrict__ tbuf, const int* __restrict__ tcntT,
                     const int* __restrict__ tstartT, const int* __restrict__ hbase,
                     int* __restrict__ rowptr, int* __restrict__ esrc,
                     int n, int E, int T, int B) {
    __shared__ int hist[NB];
    __shared__ int wsum[4];
    const int b  = blockIdx.x;
    const int e0 = hbase[(size_t)b * T];
    if (threadIdx.x < NB) hist[threadIdx.x] = 0;
    __syncthreads();
    for (int t = threadIdx.x; t < T; t += 512) {
        const int c  = tcntT[(size_t)b * T + t];
        const int ls = tstartT[(size_t)b * T + t];
        const unsigned* __restrict__ src = tbuf + (size_t)t * TILE_E + ls;
        for (int k = 0; k < c; ++k) atomicAdd(&hist[src[k] >> 17], 1);
    }
    __syncthreads();
    if (threadIdx.x < NB) {
        const int lane = threadIdx.x & 63;
        const int wid  = threadIdx.x >> 6;    // 0..3
        const int v = hist[threadIdx.x];
        int incl = v;
#pragma unroll
        for (int off = 1; off < 64; off <<= 1) {
            int tt = __shfl_up(incl, off, 64);
            if (lane >= off) incl += tt;
        }
        if (lane == 63) wsum[wid] = incl;
    }
    __syncthreads();
    if (threadIdx.x < NB) {
        const int wid = threadIdx.x >> 6;
        const int v   = hist[threadIdx.x];
        const int lane = threadIdx.x & 63;
        int incl = v;
#pragma unroll
        for (int off = 1; off < 64; off <<= 1) {
            int tt = __shfl_up(incl, off, 64);
            if (lane >= off) incl += tt;
        }
        int woff = 0;
        for (int w = 0; w < wid; ++w) woff += wsum[w];
        const int excl = woff + incl - v;
        hist[threadIdx.x] = e0 + excl;          // write pointers
        const int node = b * NB + (int)threadIdx.x;
        if (node < n) rowptr[node] = e0 + excl;
    }
    if (b == 0 && threadIdx.x == 0) rowptr[n] = E;
    __syncthreads();
    for (int t = threadIdx.x; t < T; t += 512) {
        const int c  = tcntT[(size_t)b * T + t];
        const int ls = tstartT[(size_t)b * T + t];
        const unsigned* __restrict__ src = tbuf + (size_t)t * TILE_E + ls;
        for (int k = 0; k < c; ++k) {
            const unsigned wv = src[k];
            const int pos = atomicAdd(&hist[wv >> 17], 1);
            esrc[pos] = (int)((wv & 0x1FFFFu) << 8);   // byte offset of 256B row
        }
    }
}

// ---------------------------------------------------------------------------
// Weight packing: WT[c][k] = Wcat[k][c] as bf16, row stride WT_LD.
// ---------------------------------------------------------------------------
__global__ __launch_bounds__(256)
void pack_dual_kernel(const float* __restrict__ Wl, const float* __restrict__ Wr,
                      ushort_t* __restrict__ WT) {
    int i = blockIdx.x * 256 + threadIdx.x;
    if (i >= 128 * 128) return;
    int k = i >> 7, c = i & 127;
    float v = (c < 64) ? Wl[k * 64 + c] : Wr[k * 64 + (c - 64)];
    WT[c * WT_LD + k] = f2bf(v);
}
__global__ __launch_bounds__(256)
void pack_stack_kernel(const float* __restrict__ Wl, const float* __restrict__ Wr,
                       ushort_t* __restrict__ WT) {
    int i = blockIdx.x * 256 + threadIdx.x;
    if (i >= 128 * 128) return;
    int k = i >> 7, c = i & 127;
    float v = (k < 64) ? Wl[k * 128 + c] : Wr[(k - 64) * 128 + c];
    WT[c * WT_LD + k] = f2bf(v);
}

// ---------------------------------------------------------------------------
// MFMA GEMM (operand-swapped): C[n][128] = A[n][128] @ W[128][128].
// acc = mfma(W_frag, act_frag): lane owns act row (lane&15), reg dim = 4
// consecutive output channels -> packed 8B stores. W in LDS, 64 rows/block.
// A_FP32: fp32 input (layer 1's x); else bf16 [n][128].
// ---------------------------------------------------------------------------
template <bool A_FP32, bool TANH_BIAS>
__global__ __launch_bounds__(256)
void mfma_gemm_kernel(const void* __restrict__ Av, const ushort_t* __restrict__ WT,
                      const float* __restrict__ bias, ushort_t* __restrict__ C, int n) {
    __shared__ ushort_t sW[128 * WT_LD];
    {
        const uint4* gsrc = (const uint4*)WT;
        uint4* ldst = (uint4*)sW;
        for (int i = threadIdx.x; i < 128 * WT_LD * 2 / 16; i += 256) ldst[i] = gsrc[i];
    }
    __syncthreads();
    const int lane = threadIdx.x & 63;
    const int wave = threadIdx.x >> 6;
    const int kg   = lane >> 4;       // 0..3
    const int row0 = blockIdx.x * 64 + wave * 16;
    const int rA   = min(row0 + (lane & 15), n - 1);

    bf16x8 a[4];
    if (A_FP32) {
        const float* A = (const float*)Av;
#pragma unroll
        for (int t = 0; t < 4; ++t) {
            const float4 lo = *(const float4*)(A + (size_t)rA * 128 + t * 32 + kg * 8);
            const float4 hi = *(const float4*)(A + (size_t)rA * 128 + t * 32 + kg * 8 + 4);
            const ushort4 u0 = f4_to_bf4(lo), u1 = f4_to_bf4(hi);
            bf16x8 av;
            av[0] = (short)u0.x; av[1] = (short)u0.y; av[2] = (short)u0.z; av[3] = (short)u0.w;
            av[4] = (short)u1.x; av[5] = (short)u1.y; av[6] = (short)u1.z; av[7] = (short)u1.w;
            a[t] = av;
        }
    } else {
        const ushort_t* A = (const ushort_t*)Av;
#pragma unroll
        for (int t = 0; t < 4; ++t)
            a[t] = *(const bf16x8*)(A + (size_t)rA * 128 + t * 32 + kg * 8);
    }

    f32x4 acc[8];
#pragma unroll
    for (int ct = 0; ct < 8; ++ct) acc[ct] = (f32x4)(0.f);

#pragma unroll
    for (int ct = 0; ct < 8; ++ct) {
        const int c0 = ct * 16 + (lane & 15);   // output channel held as A-row
#pragma unroll
        for (int t = 0; t < 4; ++t) {
            const bf16x8 b = *(const bf16x8*)(sW + (size_t)c0 * WT_LD + t * 32 + kg * 8);
            acc[ct] = __builtin_amdgcn_mfma_f32_16x16x32_bf16(b, a[t], acc[ct], 0, 0, 0);
        }
    }

    const int r = row0 + (lane & 15);
    if (r < n) {
        ushort_t* crow = C + (size_t)r * 128 + kg * 4;
#pragma unroll
        for (int ct = 0; ct < 8; ++ct) {
            float v0 = acc[ct][0], v1 = acc[ct][1], v2 = acc[ct][2], v3 = acc[ct][3];
            if (TANH_BIAS) {
                const float4 bv = *(const float4*)(bias + ct * 16 + kg * 4);
                v0 = tanhf(v0 + bv.x); v1 = tanhf(v1 + bv.y);
                v2 = tanhf(v2 + bv.z); v3 = tanhf(v3 + bv.w);
            }
            uint2 pk;
            pk.x = pack_bf2(v0, v1);
            pk.y = pack_bf2(v2, v3);
            *(uint2*)(crow + ct * 16) = pk;
        }
    }
}

// ---------------------------------------------------------------------------
// Gather-mean + residual + bias + tanh over interleaved pq[n][128]
// (p = cols 0..63 read by src, q = cols 64..127 read by node).
// esrc = byte offsets of 256B rows. 4-edge unroll (R10-proven pattern).
// MODE 0: write h1 into ah[node][64+4c] (stride 128).
// MODE 1: fused head (Wlin/blin in LDS) -> out[n][10] fp32, 16-lane reduce.
// ---------------------------------------------------------------------------
template <int MODE>
__global__ __launch_bounds__(THREADS)
void gather_fuse_kernel(const int* __restrict__ rowptr, const int* __restrict__ esrc,
                        const ushort_t* __restrict__ pq, const float* __restrict__ bias,
                        ushort_t* __restrict__ hout,
                        const float* __restrict__ Wlin, const float* __restrict__ blin,
                        float* __restrict__ out, int n) {
    constexpr int CH  = 16;
    constexpr int NPB = THREADS / CH;
    __shared__ float sW[MODE == 1 ? 640 : 1];
    __shared__ float sb[MODE == 1 ? 10 : 1];
    if (MODE == 1) {
        for (int i = threadIdx.x; i < 640; i += THREADS) sW[i] = Wlin[i];
        if (threadIdx.x < 10) sb[threadIdx.x] = blin[threadIdx.x];
        __syncthreads();
    }
    const int node = blockIdx.x * NPB + (int)(threadIdx.x / CH);
    const int c    = threadIdx.x & (CH - 1);
    if (node >= n) return;
    const int begin = rowptr[node];
    const int end   = rowptr[node + 1];
    const char* __restrict__ base = (const char*)pq + 8 * c;
    float ax = 0.f, ay = 0.f, az = 0.f, aw = 0.f;
    int e = begin;
    for (; e + 4 <= end; e += 4) {
        const int o0 = esrc[e + 0], o1 = esrc[e + 1], o2 = esrc[e + 2], o3 = esrc[e + 3];
        const uint2 d0 = *(const uint2*)(base + o0);
        const uint2 d1 = *(const uint2*)(base + o1);
        const uint2 d2 = *(const uint2*)(base + o2);
        const uint2 d3 = *(const uint2*)(base + o3);
        acc_pair(d0.x, ax, ay); acc_pair(d0.y, az, aw);
        acc_pair(d1.x, ax, ay); acc_pair(d1.y, az, aw);
        acc_pair(d2.x, ax, ay); acc_pair(d2.y, az, aw);
        acc_pair(d3.x, ax, ay); acc_pair(d3.y, az, aw);
    }
    for (; e < end; ++e) {
        const uint2 d = *(const uint2*)(base + esrc[e]);
        acc_pair(d.x, ax, ay); acc_pair(d.y, az, aw);
    }
    const float inv = 1.0f / fmaxf((float)(end - begin), 1.0f);
    const float4 qv = bf4_to_f4(*(const ushort4*)(pq + (size_t)node * 128 + 64 + 4 * c));
    const float4 bv = *(const float4*)(bias + 4 * c);
    float4 o;
    o.x = tanhf(ax * inv + qv.x + bv.x);
    o.y = tanhf(ay * inv + qv.y + bv.y);
    o.z = tanhf(az * inv + qv.z + bv.z);
    o.w = tanhf(aw * inv + qv.w + bv.w);
    if (MODE == 0) {
        *(ushort4*)(hout + (size_t)node * 128 + 64 + 4 * c) = f4_to_bf4(o);
    } else {
        // fused head: lane c holds channels 4c..4c+3 of h3
        float tot[10];
        const float* __restrict__ w0 = sW + (4 * c + 0) * 10;
        const float* __restrict__ w1 = sW + (4 * c + 1) * 10;
        const float* __restrict__ w2 = sW + (4 * c + 2) * 10;
        const float* __restrict__ w3 = sW + (4 * c + 3) * 10;
#pragma unroll
        for (int j = 0; j < 10; ++j)
            tot[j] = o.x * w0[j] + o.y * w1[j] + o.z * w2[j] + o.w * w3[j];
#pragma unroll
        for (int m = 1; m < 16; m <<= 1) {
#pragma unroll
            for (int j = 0; j < 10; ++j) tot[j] += __shfl_xor(tot[j], m, 64);
        }
        if (c == 0) {
            float* orow = out + (size_t)node * 10;
#pragma unroll
            for (int j = 0; j < 10; ++j) orow[j] = tot[j] + sb[j];
        }
    }
}

// ---------------------------------------------------------------------------
// gather-mean into ah cols 0..63 reading ah cols 64..127 (disjoint halves).
// ---------------------------------------------------------------------------
__global__ __launch_bounds__(THREADS)
void gather_mean_kernel(const int* __restrict__ rowptr, const int* __restrict__ esrc,
                        ushort_t* __restrict__ ah, int n) {
    constexpr int CH  = 16;
    constexpr int NPB = THREADS / CH;
    const int node = blockIdx.x * NPB + (int)(threadIdx.x / CH);
    const int c    = threadIdx.x & (CH - 1);
    if (node >= n) return;
    const int begin = rowptr[node];
    const int end   = rowptr[node + 1];
    const char* __restrict__ base = (const char*)ah + 128 + 8 * c;
    float ax = 0.f, ay = 0.f, az = 0.f, aw = 0.f;
    int e = begin;
    for (; e + 4 <= end; e += 4) {
        const int o0 = esrc[e + 0], o1 = esrc[e + 1], o2 = esrc[e + 2], o3 = esrc[e + 3];
        const uint2 d0 = *(const uint2*)(base + o0);
        const uint2 d1 = *(const uint2*)(base + o1);
        const uint2 d2 = *(const uint2*)(base + o2);
        const uint2 d3 = *(const uint2*)(base + o3);
        acc_pair(d0.x, ax, ay); acc_pair(d0.y, az, aw);
        acc_pair(d1.x, ax, ay); acc_pair(d1.y, az, aw);
        acc_pair(d2.x, ax, ay); acc_pair(d2.y, az, aw);
        acc_pair(d3.x, ax, ay); acc_pair(d3.y, az, aw);
    }
    for (; e < end; ++e) {
        const uint2 d = *(const uint2*)(base + esrc[e]);
        acc_pair(d.x, ax, ay); acc_pair(d.y, az, aw);
    }
    const float inv = 1.0f / fmaxf((float)(end - begin), 1.0f);
    ushort4 o = f4_to_bf4(make_float4(ax * inv, ay * inv, az * inv, aw * inv));
    *(ushort4*)(ah + (size_t)node * 128 + 4 * c) = o;
}

extern "C" void kernel_launch(void* const* d_in, const int* in_sizes, int n_in,
                              void* d_out, int out_size, void* d_ws, size_t ws_size,
                              hipStream_t stream) {
    const float* x    = (const float*)d_in[0];
    const void*  ei   = d_in[1];
    const float* W1l  = (const float*)d_in[2];
    const float* W1r  = (const float*)d_in[3];
    const float* b1   = (const float*)d_in[4];
    const float* W2l  = (const float*)d_in[5];
    const float* W2r  = (const float*)d_in[6];
    const float* b2   = (const float*)d_in[7];
    const float* W3l  = (const float*)d_in[8];
    const float* W3r  = (const float*)d_in[9];
    const float* b3   = (const float*)d_in[10];
    const float* Wlin = (const float*)d_in[11];
    const float* blin = (const float*)d_in[12];
    float* out = (float*)d_out;

    const int n = in_sizes[0] / 128;           // 100000
    const int E = in_sizes[1] / 2;             // 1600000
    const int B = (n + NB - 1) / NB;           // buckets (391)
    const int T = (E + TILE_E - 1) / TILE_E;   // sort tiles (1563)
    const int Ctot = B * T;

    // --- workspace carve-up (~100 MB) ---
    char* ws = (char*)d_ws;
    size_t off = 0;
    auto carve = [&](size_t bytes) {
        void* p = ws + off;
        off += (bytes + 255) & ~(size_t)255;
        return p;
    };
    int*      flag    = (int*)     carve(256);
    int*      bsum    = (int*)     carve(8192);
    unsigned* tbuf    = (unsigned*)carve((size_t)T * TILE_E * 4);
    int*      tcnt    = (int*)     carve((size_t)Ctot * 4);
    int*      tstart  = (int*)     carve((size_t)Ctot * 4);
    int*      tcntT   = (int*)     carve((size_t)Ctot * 4);
    int*      tstartT = (int*)     carve((size_t)Ctot * 4);
    int*      hbase   = (int*)     carve((size_t)(Ctot + 1) * 4);
    int*      rowptr  = (int*)     carve((size_t)(n + 1) * 4);
    int*      esrc    = (int*)     carve((size_t)E * 4);
    ushort_t* WT1     = (ushort_t*)carve((size_t)128 * WT_LD * 2);
    ushort_t* WT2     = (ushort_t*)carve((size_t)128 * WT_LD * 2);
    ushort_t* WT3     = (ushort_t*)carve((size_t)128 * WT_LD * 2);
    ushort_t* pq      = (ushort_t*)carve((size_t)n * 128 * 2);  // [p|q] interleaved
    ushort_t* ah      = (ushort_t*)carve((size_t)n * 128 * 2);  // [agg|h1] interleaved
    ushort_t* h2      = (ushort_t*)carve((size_t)n * 128 * 2);
    (void)ws_size;

    const int cscan   = (Ctot + 1023) / 1024;
    const int gblocks = (n + 63) / 64;

    // --- weight packing (tiny) ---
    pack_dual_kernel <<<64, 256, 0, stream>>>(W1l, W1r, WT1);
    pack_stack_kernel<<<64, 256, 0, stream>>>(W2l, W2r, WT2);
    pack_dual_kernel <<<64, 256, 0, stream>>>(W3l, W3r, WT3);

    // --- tiled two-level edge sort (once; graph shared by all layers) ---
    detect_kernel<<<1, 64, 0, stream>>>((const unsigned*)ei, flag);
    tilesort_kernel<<<T, 512, 0, stream>>>(ei, flag, tbuf, tcnt, tstart, E, B);
    {
        dim3 tg((B + 31) / 32, (T + 31) / 32);
        transpose2_kernel<<<tg, 256, 0, stream>>>(tcnt, tstart, tcntT, tstartT, T, B);
    }
    scan_partial_kernel<<<cscan, 256, 0, stream>>>(tcntT, bsum, Ctot);
    scan_bsum_kernel<<<1, 1024, 0, stream>>>(bsum, hbase + Ctot, cscan);
    scan_final_kernel<<<cscan, 256, 0, stream>>>(tcntT, bsum, hbase, Ctot);
    finesort_kernel<<<B, 512, 0, stream>>>(tbuf, tcntT, tstartT, hbase,
                                           rowptr, esrc, n, E, T, B);

    // --- layer 1: pq = x @ [W1l|W1r]; h1 = tanh(mean(p) + q + b1) -> ah[:,64:] ---
    mfma_gemm_kernel<true, false><<<gblocks, 256, 0, stream>>>(x, WT1, nullptr, pq, n);
    gather_fuse_kernel<0><<<(n + 15) / 16, THREADS, 0, stream>>>(
        rowptr, esrc, pq, b1, ah, nullptr, nullptr, nullptr, n);

    // --- layer 2: ah[:,0:64] = mean(h1); h2 = tanh(ah @ [W2l;W2r] + b2) ---
    gather_mean_kernel<<<(n + 15) / 16, THREADS, 0, stream>>>(rowptr, esrc, ah, n);
    mfma_gemm_kernel<false, true><<<gblocks, 256, 0, stream>>>(ah, WT2, b2, h2, n);

    // --- layer 3: pq = h2 @ [W3l|W3r]; out = head(tanh(mean(p)+q+b3)) fused ---
    mfma_gemm_kernel<false, false><<<gblocks, 256, 0, stream>>>(h2, WT3, nullptr, pq, n);
    gather_fuse_kernel<1><<<(n + 15) / 16, THREADS, 0, stream>>>(
        rowptr, esrc, pq, b3, nullptr, Wlin, blin, out, n);
}

// Round 15
// 243.592 us; speedup vs baseline: 1.0255x; 1.0255x over previous
//
#include <hip/hip_runtime.h>

#define THREADS 256
#define NB 256                  // nodes per bucket
#define NB_SHIFT 8
#define TILE_E 1024             // edges per sort tile
#define EPT 2                   // edges per thread in tilesort (TILE_E/512)
#define BMAXPAD 512             // padded bucket-hist size in tilesort
#define WT_LD 136               // padded K stride for packed weights

typedef unsigned short ushort_t;
typedef __attribute__((ext_vector_type(8))) short bf16x8;
typedef __attribute__((ext_vector_type(4))) float f32x4;

__device__ __forceinline__ unsigned short f2bf(float f) {
    unsigned u = __float_as_uint(f);
    u += 0x7fff + ((u >> 16) & 1);   // round-to-nearest-even
    return (unsigned short)(u >> 16);
}
__device__ __forceinline__ float bf2f(unsigned short s) {
    return __uint_as_float((unsigned)s << 16);
}
__device__ __forceinline__ float4 bf4_to_f4(ushort4 u) {
    return make_float4(bf2f(u.x), bf2f(u.y), bf2f(u.z), bf2f(u.w));
}
__device__ __forceinline__ ushort4 f4_to_bf4(float4 v) {
    ushort4 o;
    o.x = f2bf(v.x); o.y = f2bf(v.y); o.z = f2bf(v.z); o.w = f2bf(v.w);
    return o;
}
// pack two f32 -> u32 of two bf16 (lo first)
__device__ __forceinline__ unsigned pack_bf2(float a, float b) {
    return (unsigned)f2bf(a) | ((unsigned)f2bf(b) << 16);
}
// junk-mantissa pair accumulate: lo exact, hi carries <=2^-8 rel mantissa noise
__device__ __forceinline__ void acc_pair(unsigned u, float& lo, float& hi) {
    lo += __uint_as_float(u << 16);
    hi += __uint_as_float(u);
}

// ---------------------------------------------------------------------------
// Edge-index dtype detection.
// ---------------------------------------------------------------------------
__global__ __launch_bounds__(64)
void detect_kernel(const unsigned* __restrict__ ei_words, int* __restrict__ flag) {
    if (threadIdx.x == 0 && blockIdx.x == 0) {
        int allzero = 1;
        for (int i = 0; i < 64; ++i) {
            if (ei_words[2 * i + 1] != 0u) { allzero = 0; break; }
        }
        *flag = allzero;
    }
}

__device__ __forceinline__ void load_edge(const void* ei, int is64, int E, int i,
                                          int& s, int& t) {
    if (is64) {
        const long long* p = (const long long*)ei;
        s = (int)p[i];
        t = (int)p[E + i];
    } else {
        const int* p = (const int*)ei;
        s = p[i];
        t = p[E + i];
    }
}

// ---------------------------------------------------------------------------
// Tile sort: block t owns edges [t*TILE_E, (t+1)*TILE_E). 512 threads, EPT=2.
// ---------------------------------------------------------------------------
__global__ __launch_bounds__(512)
void tilesort_kernel(const void* __restrict__ ei, const int* __restrict__ flag,
                     unsigned* __restrict__ tbuf, int* __restrict__ tcnt,
                     int* __restrict__ tstart, int E, int B) {
    __shared__ int hist[BMAXPAD];
    __shared__ int wsum[8];
    const int t   = blockIdx.x;
    const int e0  = t * TILE_E;
    const int is64 = *flag;
    unsigned w[EPT];
    unsigned short bk[EPT];
    hist[threadIdx.x] = 0;
    __syncthreads();
#pragma unroll
    for (int k = 0; k < EPT; ++k) {
        const int i = e0 + k * 512 + (int)threadIdx.x;
        bk[k] = 0xFFFFu;
        w[k]  = 0u;
        if (i < E) {
            int s, d;
            load_edge(ei, is64, E, i, s, d);
            w[k]  = (unsigned)s | ((unsigned)(d & (NB - 1)) << 17);
            bk[k] = (unsigned short)(d >> NB_SHIFT);
            atomicAdd(&hist[bk[k]], 1);
        }
    }
    __syncthreads();
    const int lane = threadIdx.x & 63;
    const int wid  = threadIdx.x >> 6;     // 0..7
    const int v = hist[threadIdx.x];
    int incl = v;
#pragma unroll
    for (int off = 1; off < 64; off <<= 1) {
        int tt = __shfl_up(incl, off, 64);
        if (lane >= off) incl += tt;
    }
    if (lane == 63) wsum[wid] = incl;
    __syncthreads();   // wsum ready; all hist reads complete
    int woff = 0;
    for (int ww = 0; ww < wid; ++ww) woff += wsum[ww];
    const int excl = woff + incl - v;
    hist[threadIdx.x] = excl;              // becomes write-pointer array
    const int b = threadIdx.x;
    if (b < B) { tcnt[(size_t)t * B + b] = v; tstart[(size_t)t * B + b] = excl; }
    __syncthreads();
#pragma unroll
    for (int k = 0; k < EPT; ++k) {
        if (bk[k] != 0xFFFFu) {
            const int pos = atomicAdd(&hist[bk[k]], 1);
            tbuf[(size_t)t * TILE_E + pos] = w[k];
        }
    }
}

// ---------------------------------------------------------------------------
// Transpose tcnt/tstart [T][B] -> [B][T] via 32x32 LDS tiles.
// ---------------------------------------------------------------------------
__global__ __launch_bounds__(256)
void transpose2_kernel(const int* __restrict__ tcnt, const int* __restrict__ tstart,
                       int* __restrict__ tcntT, int* __restrict__ tstartT,
                       int T, int B) {
    __shared__ int ta[32][33];
    __shared__ int tb[32][33];
    const int bx = blockIdx.x;            // along B
    const int by = blockIdx.y;            // along T
    const int tx = threadIdx.x & 31;
    const int ty = threadIdx.x >> 5;      // 0..7
#pragma unroll
    for (int r = 0; r < 4; ++r) {
        const int trow = by * 32 + ty * 4 + r;
        const int bcol = bx * 32 + tx;
        if (trow < T && bcol < B) {
            ta[ty * 4 + r][tx] = tcnt[(size_t)trow * B + bcol];
            tb[ty * 4 + r][tx] = tstart[(size_t)trow * B + bcol];
        }
    }
    __syncthreads();
#pragma unroll
    for (int r = 0; r < 4; ++r) {
        const int brow = bx * 32 + ty * 4 + r;
        const int tcol = by * 32 + tx;
        if (brow < B && tcol < T) {
            tcntT[(size_t)brow * T + tcol]   = ta[tx][ty * 4 + r];
            tstartT[(size_t)brow * T + tcol] = tb[tx][ty * 4 + r];
        }
    }
}

// ---------------------------------------------------------------------------
// Scan over tcntT (bucket-major) -> hbase.
// ---------------------------------------------------------------------------
__global__ __launch_bounds__(256)
void scan_partial_kernel(const int* __restrict__ cnt, int* __restrict__ bsum, int n) {
    const int base = blockIdx.x * 1024;
    int v = 0;
    for (int i = threadIdx.x; i < 1024; i += 256) {
        const int idx = base + i;
        v += (idx < n) ? cnt[idx] : 0;
    }
#pragma unroll
    for (int off = 32; off > 0; off >>= 1) v += __shfl_down(v, off, 64);
    __shared__ int ws[4];
    if ((threadIdx.x & 63) == 0) ws[threadIdx.x >> 6] = v;
    __syncthreads();
    if (threadIdx.x == 0) bsum[blockIdx.x] = ws[0] + ws[1] + ws[2] + ws[3];
}

__global__ __launch_bounds__(1024)
void scan_bsum_kernel(int* __restrict__ bsum, int* __restrict__ total, int nb) {
    __shared__ int wsum[16];
    const int lane = threadIdx.x & 63;
    const int wid  = threadIdx.x >> 6;    // 0..15
    int run = 0;
    for (int base = 0; base < nb; base += 1024) {
        const int i = base + (int)threadIdx.x;
        const int v = (i < nb) ? bsum[i] : 0;
        int incl = v;
#pragma unroll
        for (int off = 1; off < 64; off <<= 1) {
            int t = __shfl_up(incl, off, 64);
            if (lane >= off) incl += t;
        }
        if (lane == 63) wsum[wid] = incl;
        __syncthreads();
        if (wid == 0) {
            int wv = (lane < 16) ? wsum[lane] : 0;
#pragma unroll
            for (int off = 1; off < 16; off <<= 1) {
                int t = __shfl_up(wv, off, 64);
                if (lane >= off) wv += t;
            }
            if (lane < 16) wsum[lane] = wv;
        }
        __syncthreads();
        const int wbase = (wid > 0) ? wsum[wid - 1] : 0;
        const int tot   = wsum[15];
        if (i < nb) bsum[i] = run + wbase + incl - v;
        run += tot;
        __syncthreads();
    }
    if (threadIdx.x == 0) *total = run;
}

__global__ __launch_bounds__(256)
void scan_final_kernel(const int* __restrict__ cnt, const int* __restrict__ bsum,
                       int* __restrict__ outp, int n) {
    const int base = blockIdx.x * 1024 + threadIdx.x * 4;
    int a0 = 0, a1 = 0, a2 = 0, a3 = 0;
    if (base + 0 < n) a0 = cnt[base + 0];
    if (base + 1 < n) a1 = cnt[base + 1];
    if (base + 2 < n) a2 = cnt[base + 2];
    if (base + 3 < n) a3 = cnt[base + 3];
    const int mysum = a0 + a1 + a2 + a3;
    const int lane = threadIdx.x & 63;
    const int wid  = threadIdx.x >> 6;
    int incl = mysum;
#pragma unroll
    for (int off = 1; off < 64; off <<= 1) {
        int t = __shfl_up(incl, off, 64);
        if (lane >= off) incl += t;
    }
    __shared__ int ws[4];
    if (lane == 63) ws[wid] = incl;
    __syncthreads();
    int woff = 0;
    for (int w = 0; w < wid; ++w) woff += ws[w];
    int pre = bsum[blockIdx.x] + woff + (incl - mysum);
    if (base + 0 < n) outp[base + 0] = pre; pre += a0;
    if (base + 1 < n) outp[base + 1] = pre; pre += a1;
    if (base + 2 < n) outp[base + 2] = pre; pre += a2;
    if (base + 3 < n) outp[base + 3] = pre;
}

// ---------------------------------------------------------------------------
// Fine sort: one 512-thread block per bucket. esrc stores BYTE offsets
// (src*128) of the source's dense 128B feature row.
// ---------------------------------------------------------------------------
__global__ __launch_bounds__(512)
void finesort_kernel(const unsigned* __restrict__ tbuf, const int* __restrict__ tcntT,
                     const int* __restrict__ tstartT, const int* __restrict__ hbase,
                     int* __restrict__ rowptr, int* __restrict__ esrc,
                     int n, int E, int T, int B) {
    __shared__ int hist[NB];
    __shared__ int wsum[4];
    const int b  = blockIdx.x;
    const int e0 = hbase[(size_t)b * T];
    if (threadIdx.x < NB) hist[threadIdx.x] = 0;
    __syncthreads();
    for (int t = threadIdx.x; t < T; t += 512) {
        const int c  = tcntT[(size_t)b * T + t];
        const int ls = tstartT[(size_t)b * T + t];
        const unsigned* __restrict__ src = tbuf + (size_t)t * TILE_E + ls;
        for (int k = 0; k < c; ++k) atomicAdd(&hist[src[k] >> 17], 1);
    }
    __syncthreads();
    if (threadIdx.x < NB) {
        const int lane = threadIdx.x & 63;
        const int wid  = threadIdx.x >> 6;    // 0..3
        const int v = hist[threadIdx.x];
        int incl = v;
#pragma unroll
        for (int off = 1; off < 64; off <<= 1) {
            int tt = __shfl_up(incl, off, 64);
            if (lane >= off) incl += tt;
        }
        if (lane == 63) wsum[wid] = incl;
    }
    __syncthreads();
    if (threadIdx.x < NB) {
        const int wid = threadIdx.x >> 6;
        const int v   = hist[threadIdx.x];
        const int lane = threadIdx.x & 63;
        int incl = v;
#pragma unroll
        for (int off = 1; off < 64; off <<= 1) {
            int tt = __shfl_up(incl, off, 64);
            if (lane >= off) incl += tt;
        }
        int woff = 0;
        for (int w = 0; w < wid; ++w) woff += wsum[w];
        const int excl = woff + incl - v;
        hist[threadIdx.x] = e0 + excl;          // write pointers
        const int node = b * NB + (int)threadIdx.x;
        if (node < n) rowptr[node] = e0 + excl;
    }
    if (b == 0 && threadIdx.x == 0) rowptr[n] = E;
    __syncthreads();
    for (int t = threadIdx.x; t < T; t += 512) {
        const int c  = tcntT[(size_t)b * T + t];
        const int ls = tstartT[(size_t)b * T + t];
        const unsigned* __restrict__ src = tbuf + (size_t)t * TILE_E + ls;
        for (int k = 0; k < c; ++k) {
            const unsigned wv = src[k];
            const int pos = atomicAdd(&hist[wv >> 17], 1);
            esrc[pos] = (int)((wv & 0x1FFFFu) << 7);   // byte offset of dense 128B row
        }
    }
}

// ---------------------------------------------------------------------------
// Weight packing: WT[c][k] = Wcat[k][c] as bf16, row stride WT_LD.
// ---------------------------------------------------------------------------
__global__ __launch_bounds__(256)
void pack_dual_kernel(const float* __restrict__ Wl, const float* __restrict__ Wr,
                      ushort_t* __restrict__ WT) {
    int i = blockIdx.x * 256 + threadIdx.x;
    if (i >= 128 * 128) return;
    int k = i >> 7, c = i & 127;
    float v = (c < 64) ? Wl[k * 64 + c] : Wr[k * 64 + (c - 64)];
    WT[c * WT_LD + k] = f2bf(v);
}
__global__ __launch_bounds__(256)
void pack_stack_kernel(const float* __restrict__ Wl, const float* __restrict__ Wr,
                       ushort_t* __restrict__ WT) {
    int i = blockIdx.x * 256 + threadIdx.x;
    if (i >= 128 * 128) return;
    int k = i >> 7, c = i & 127;
    float v = (k < 64) ? Wl[k * 128 + c] : Wr[(k - 64) * 128 + c];
    WT[c * WT_LD + k] = f2bf(v);
}

// ---------------------------------------------------------------------------
// MFMA GEMM (operand-swapped): out[n][128] = A[n][128] @ W[128][128].
// AMODE 0: A fp32 [n][128]; 1: A bf16 dual [n][64]+[n][64]; 2: A bf16 [n][128].
// OUT_SPLIT: channels 0..63 -> C1 [n][64], 64..127 -> C2 [n][64]; else C1 [n][128].
// ---------------------------------------------------------------------------
template <int AMODE, bool TANH_BIAS, bool OUT_SPLIT>
__global__ __launch_bounds__(256)
void mfma_gemm_kernel(const void* __restrict__ Av1, const void* __restrict__ Av2,
                      const ushort_t* __restrict__ WT, const float* __restrict__ bias,
                      ushort_t* __restrict__ C1, ushort_t* __restrict__ C2, int n) {
    __shared__ ushort_t sW[128 * WT_LD];
    {
        const uint4* gsrc = (const uint4*)WT;
        uint4* ldst = (uint4*)sW;
        for (int i = threadIdx.x; i < 128 * WT_LD * 2 / 16; i += 256) ldst[i] = gsrc[i];
    }
    __syncthreads();
    const int lane = threadIdx.x & 63;
    const int wave = threadIdx.x >> 6;
    const int kg   = lane >> 4;       // 0..3
    const int row0 = blockIdx.x * 64 + wave * 16;
    const int rA   = min(row0 + (lane & 15), n - 1);

    bf16x8 a[4];
    if (AMODE == 0) {
        const float* A = (const float*)Av1;
#pragma unroll
        for (int t = 0; t < 4; ++t) {
            const float4 lo = *(const float4*)(A + (size_t)rA * 128 + t * 32 + kg * 8);
            const float4 hi = *(const float4*)(A + (size_t)rA * 128 + t * 32 + kg * 8 + 4);
            const ushort4 u0 = f4_to_bf4(lo), u1 = f4_to_bf4(hi);
            bf16x8 av;
            av[0] = (short)u0.x; av[1] = (short)u0.y; av[2] = (short)u0.z; av[3] = (short)u0.w;
            av[4] = (short)u1.x; av[5] = (short)u1.y; av[6] = (short)u1.z; av[7] = (short)u1.w;
            a[t] = av;
        }
    } else if (AMODE == 1) {
        const ushort_t* A1 = (const ushort_t*)Av1;
        const ushort_t* A2 = (const ushort_t*)Av2;
        a[0] = *(const bf16x8*)(A1 + (size_t)rA * 64 + 0 + kg * 8);
        a[1] = *(const bf16x8*)(A1 + (size_t)rA * 64 + 32 + kg * 8);
        a[2] = *(const bf16x8*)(A2 + (size_t)rA * 64 + 0 + kg * 8);
        a[3] = *(const bf16x8*)(A2 + (size_t)rA * 64 + 32 + kg * 8);
    } else {
        const ushort_t* A = (const ushort_t*)Av1;
#pragma unroll
        for (int t = 0; t < 4; ++t)
            a[t] = *(const bf16x8*)(A + (size_t)rA * 128 + t * 32 + kg * 8);
    }

    f32x4 acc[8];
#pragma unroll
    for (int ct = 0; ct < 8; ++ct) acc[ct] = (f32x4)(0.f);

#pragma unroll
    for (int ct = 0; ct < 8; ++ct) {
        const int c0 = ct * 16 + (lane & 15);   // output channel held as A-row
#pragma unroll
        for (int t = 0; t < 4; ++t) {
            const bf16x8 b = *(const bf16x8*)(sW + (size_t)c0 * WT_LD + t * 32 + kg * 8);
            acc[ct] = __builtin_amdgcn_mfma_f32_16x16x32_bf16(b, a[t], acc[ct], 0, 0, 0);
        }
    }

    const int r = row0 + (lane & 15);
    if (r < n) {
#pragma unroll
        for (int ct = 0; ct < 8; ++ct) {
            float v0 = acc[ct][0], v1 = acc[ct][1], v2 = acc[ct][2], v3 = acc[ct][3];
            if (TANH_BIAS) {
                const float4 bv = *(const float4*)(bias + ct * 16 + kg * 4);
                v0 = tanhf(v0 + bv.x); v1 = tanhf(v1 + bv.y);
                v2 = tanhf(v2 + bv.z); v3 = tanhf(v3 + bv.w);
            }
            uint2 pk;
            pk.x = pack_bf2(v0, v1);
            pk.y = pack_bf2(v2, v3);
            if (OUT_SPLIT) {
                if (ct < 4)
                    *(uint2*)(C1 + (size_t)r * 64 + kg * 4 + ct * 16) = pk;
                else
                    *(uint2*)(C2 + (size_t)r * 64 + kg * 4 + (ct - 4) * 16) = pk;
            } else {
                *(uint2*)(C1 + (size_t)r * 128 + kg * 4 + ct * 16) = pk;
            }
        }
    }
}

// ---------------------------------------------------------------------------
// Gather-mean + residual + bias + tanh over dense p[n][64] + q[n][64].
// esrc = byte offsets of 128B rows. 8-edge unroll (measured best: R11/R12).
// MODE 0: write h1[n][64] bf16. MODE 1: fused head -> out[n][10] fp32.
// Head weights in conflict-free LDS: sWp[c][j*4+k] = Wlin[(4c+k)*10+j],
// row stride 41 floats (bank = 9c mod 32, all 16 lanes distinct; upper
// lane groups repeat addresses -> broadcast).
// ---------------------------------------------------------------------------
template <int MODE>
__global__ __launch_bounds__(THREADS)
void gather_fuse_kernel(const int* __restrict__ rowptr, const int* __restrict__ esrc,
                        const ushort_t* __restrict__ p, const ushort_t* __restrict__ q,
                        const float* __restrict__ bias, ushort_t* __restrict__ h1out,
                        const float* __restrict__ Wlin, const float* __restrict__ blin,
                        float* __restrict__ out, int n) {
    constexpr int CH  = 16;
    constexpr int NPB = THREADS / CH;
    __shared__ float sWp[MODE == 1 ? 16 * 41 : 1];
    __shared__ float sb[MODE == 1 ? 10 : 1];
    if (MODE == 1) {
        for (int i = threadIdx.x; i < 16 * 41; i += THREADS) {
            const int row = i / 41, col = i % 41;
            if (col < 40) {
                const int j = col >> 2, k = col & 3;
                sWp[i] = Wlin[(4 * row + k) * 10 + j];
            }
        }
        if (threadIdx.x < 10) sb[threadIdx.x] = blin[threadIdx.x];
        __syncthreads();
    }
    const int node = blockIdx.x * NPB + (int)(threadIdx.x / CH);
    const int c    = threadIdx.x & (CH - 1);
    if (node >= n) return;
    const int begin = rowptr[node];
    const int end   = rowptr[node + 1];
    const char* __restrict__ base = (const char*)p + 8 * c;
    float ax = 0.f, ay = 0.f, az = 0.f, aw = 0.f;
    int e = begin;
    for (; e + 8 <= end; e += 8) {
        uint2 d[8];
#pragma unroll
        for (int j = 0; j < 8; ++j) d[j] = *(const uint2*)(base + esrc[e + j]);
#pragma unroll
        for (int j = 0; j < 8; ++j) { acc_pair(d[j].x, ax, ay); acc_pair(d[j].y, az, aw); }
    }
    if (e + 4 <= end) {
        uint2 d[4];
#pragma unroll
        for (int j = 0; j < 4; ++j) d[j] = *(const uint2*)(base + esrc[e + j]);
#pragma unroll
        for (int j = 0; j < 4; ++j) { acc_pair(d[j].x, ax, ay); acc_pair(d[j].y, az, aw); }
        e += 4;
    }
    for (; e < end; ++e) {
        const uint2 d = *(const uint2*)(base + esrc[e]);
        acc_pair(d.x, ax, ay); acc_pair(d.y, az, aw);
    }
    const float inv = 1.0f / fmaxf((float)(end - begin), 1.0f);
    const float4 qv = bf4_to_f4(*(const ushort4*)(q + (size_t)node * 64 + 4 * c));
    const float4 bv = *(const float4*)(bias + 4 * c);
    float4 o;
    o.x = tanhf(ax * inv + qv.x + bv.x);
    o.y = tanhf(ay * inv + qv.y + bv.y);
    o.z = tanhf(az * inv + qv.z + bv.z);
    o.w = tanhf(aw * inv + qv.w + bv.w);
    if (MODE == 0) {
        *(ushort4*)(h1out + (size_t)node * 64 + 4 * c) = f4_to_bf4(o);
    } else {
        // fused head: lane c holds channels 4c..4c+3 of h3
        const float* __restrict__ wrow = sWp + c * 41;
        float tot[10];
#pragma unroll
        for (int j = 0; j < 10; ++j)
            tot[j] = o.x * wrow[j * 4 + 0] + o.y * wrow[j * 4 + 1]
                   + o.z * wrow[j * 4 + 2] + o.w * wrow[j * 4 + 3];
#pragma unroll
        for (int m = 1; m < 16; m <<= 1) {
#pragma unroll
            for (int j = 0; j < 10; ++j) tot[j] += __shfl_xor(tot[j], m, 64);
        }
        if (c == 0) {
            float* orow = out + (size_t)node * 10;
#pragma unroll
            for (int j = 0; j < 10; ++j) orow[j] = tot[j] + sb[j];
        }
    }
}

// ---------------------------------------------------------------------------
// gather-mean: agg[n][64] = mean over h1[n][64] rows. 8-edge unroll.
// ---------------------------------------------------------------------------
__global__ __launch_bounds__(THREADS)
void gather_mean_kernel(const int* __restrict__ rowptr, const int* __restrict__ esrc,
                        const ushort_t* __restrict__ h1, ushort_t* __restrict__ agg,
                        int n) {
    constexpr int CH  = 16;
    constexpr int NPB = THREADS / CH;
    const int node = blockIdx.x * NPB + (int)(threadIdx.x / CH);
    const int c    = threadIdx.x & (CH - 1);
    if (node >= n) return;
    const int begin = rowptr[node];
    const int end   = rowptr[node + 1];
    const char* __restrict__ base = (const char*)h1 + 8 * c;
    float ax = 0.f, ay = 0.f, az = 0.f, aw = 0.f;
    int e = begin;
    for (; e + 8 <= end; e += 8) {
        uint2 d[8];
#pragma unroll
        for (int j = 0; j < 8; ++j) d[j] = *(const uint2*)(base + esrc[e + j]);
#pragma unroll
        for (int j = 0; j < 8; ++j) { acc_pair(d[j].x, ax, ay); acc_pair(d[j].y, az, aw); }
    }
    if (e + 4 <= end) {
        uint2 d[4];
#pragma unroll
        for (int j = 0; j < 4; ++j) d[j] = *(const uint2*)(base + esrc[e + j]);
#pragma unroll
        for (int j = 0; j < 4; ++j) { acc_pair(d[j].x, ax, ay); acc_pair(d[j].y, az, aw); }
        e += 4;
    }
    for (; e < end; ++e) {
        const uint2 d = *(const uint2*)(base + esrc[e]);
        acc_pair(d.x, ax, ay); acc_pair(d.y, az, aw);
    }
    const float inv = 1.0f / fmaxf((float)(end - begin), 1.0f);
    ushort4 o = f4_to_bf4(make_float4(ax * inv, ay * inv, az * inv, aw * inv));
    *(ushort4*)(agg + (size_t)node * 64 + 4 * c) = o;
}

extern "C" void kernel_launch(void* const* d_in, const int* in_sizes, int n_in,
                              void* d_out, int out_size, void* d_ws, size_t ws_size,
                              hipStream_t stream) {
    const float* x    = (const float*)d_in[0];
    const void*  ei   = d_in[1];
    const float* W1l  = (const float*)d_in[2];
    const float* W1r  = (const float*)d_in[3];
    const float* b1   = (const float*)d_in[4];
    const float* W2l  = (const float*)d_in[5];
    const float* W2r  = (const float*)d_in[6];
    const float* b2   = (const float*)d_in[7];
    const float* W3l  = (const float*)d_in[8];
    const float* W3r  = (const float*)d_in[9];
    const float* b3   = (const float*)d_in[10];
    const float* Wlin = (const float*)d_in[11];
    const float* blin = (const float*)d_in[12];
    float* out = (float*)d_out;

    const int n = in_sizes[0] / 128;           // 100000
    const int E = in_sizes[1] / 2;             // 1600000
    const int B = (n + NB - 1) / NB;           // buckets (391)
    const int T = (E + TILE_E - 1) / TILE_E;   // sort tiles (1563)
    const int Ctot = B * T;

    // --- workspace carve-up (~100 MB) ---
    char* ws = (char*)d_ws;
    size_t off = 0;
    auto carve = [&](size_t bytes) {
        void* p = ws + off;
        off += (bytes + 255) & ~(size_t)255;
        return p;
    };
    int*      flag    = (int*)     carve(256);
    int*      bsum    = (int*)     carve(8192);
    unsigned* tbuf    = (unsigned*)carve((size_t)T * TILE_E * 4);
    int*      tcnt    = (int*)     carve((size_t)Ctot * 4);
    int*      tstart  = (int*)     carve((size_t)Ctot * 4);
    int*      tcntT   = (int*)     carve((size_t)Ctot * 4);
    int*      tstartT = (int*)     carve((size_t)Ctot * 4);
    int*      hbase   = (int*)     carve((size_t)(Ctot + 1) * 4);
    int*      rowptr  = (int*)     carve((size_t)(n + 1) * 4);
    int*      esrc    = (int*)     carve((size_t)E * 4);
    ushort_t* WT1     = (ushort_t*)carve((size_t)128 * WT_LD * 2);
    ushort_t* WT2     = (ushort_t*)carve((size_t)128 * WT_LD * 2);
    ushort_t* WT3     = (ushort_t*)carve((size_t)128 * WT_LD * 2);
    ushort_t* p       = (ushort_t*)carve((size_t)n * 64 * 2);   // dense proj (by src)
    ushort_t* q       = (ushort_t*)carve((size_t)n * 64 * 2);   // dense self-proj
    ushort_t* h1      = (ushort_t*)carve((size_t)n * 64 * 2);
    ushort_t* agg     = (ushort_t*)carve((size_t)n * 64 * 2);
    ushort_t* h2      = (ushort_t*)carve((size_t)n * 128 * 2);
    (void)ws_size;

    const int cscan   = (Ctot + 1023) / 1024;
    const int gblocks = (n + 63) / 64;

    // --- weight packing (tiny) ---
    pack_dual_kernel <<<64, 256, 0, stream>>>(W1l, W1r, WT1);
    pack_stack_kernel<<<64, 256, 0, stream>>>(W2l, W2r, WT2);
    pack_dual_kernel <<<64, 256, 0, stream>>>(W3l, W3r, WT3);

    // --- tiled two-level edge sort (once; graph shared by all layers) ---
    detect_kernel<<<1, 64, 0, stream>>>((const unsigned*)ei, flag);
    tilesort_kernel<<<T, 512, 0, stream>>>(ei, flag, tbuf, tcnt, tstart, E, B);
    {
        dim3 tg((B + 31) / 32, (T + 31) / 32);
        transpose2_kernel<<<tg, 256, 0, stream>>>(tcnt, tstart, tcntT, tstartT, T, B);
    }
    scan_partial_kernel<<<cscan, 256, 0, stream>>>(tcntT, bsum, Ctot);
    scan_bsum_kernel<<<1, 1024, 0, stream>>>(bsum, hbase + Ctot, cscan);
    scan_final_kernel<<<cscan, 256, 0, stream>>>(tcntT, bsum, hbase, Ctot);
    finesort_kernel<<<B, 512, 0, stream>>>(tbuf, tcntT, tstartT, hbase,
                                           rowptr, esrc, n, E, T, B);

    // --- layer 1: p,q = x @ [W1l|W1r]; h1 = tanh(mean(p) + q + b1) ---
    mfma_gemm_kernel<0, false, true><<<gblocks, 256, 0, stream>>>(
        x, nullptr, WT1, nullptr, p, q, n);
    gather_fuse_kernel<0><<<(n + 15) / 16, THREADS, 0, stream>>>(
        rowptr, esrc, p, q, b1, h1, nullptr, nullptr, nullptr, n);

    // --- layer 2: agg = mean(h1); h2 = tanh([agg|h1] @ [W2l;W2r] + b2) ---
    gather_mean_kernel<<<(n + 15) / 16, THREADS, 0, stream>>>(rowptr, esrc, h1, agg, n);
    mfma_gemm_kernel<1, true, false><<<gblocks, 256, 0, stream>>>(
        agg, h1, WT2, b2, h2, nullptr, n);

    // --- layer 3: p,q = h2 @ [W3l|W3r]; out = head(tanh(mean(p)+q+b3)) fused ---
    mfma_gemm_kernel<2, false, true><<<gblocks, 256, 0, stream>>>(
        h2, nullptr, WT3, nullptr, p, q, n);
    gather_fuse_kernel<1><<<(n + 15) / 16, THREADS, 0, stream>>>(
        rowptr, esrc, p, q, b3, nullptr, Wlin, blin, out, n);
}